// Round 2
// baseline (256.700 us; speedup 1.0000x reference)
//
#include <hip/hip_runtime.h>
#include <hip/hip_bf16.h>
#include <stdint.h>

using bf16 = __hip_bfloat16;

typedef __bf16 bf16x8 __attribute__((ext_vector_type(8)));
typedef float  f32x4  __attribute__((ext_vector_type(4)));
typedef int    int4v  __attribute__((ext_vector_type(4)));

constexpr int Bc = 4, Hh = 8, Dh = 128, S = 2048, Cn = 1024, O3 = 3072;
constexpr float SCALE = 0.08838834764831845f;  // 1/sqrt(128)

// ---------------------------------------------------------------------------
// BT-GEMM core: acc[m][n] += sum_k A[m][k] * B[n][k]   (bf16 in, f32 accum)
// 128x128 output tile, 256 threads = 4 waves, each wave a 64x64 quadrant
// (4x4 tiles of 16x16x32 MFMA). A,B row-major, contiguous in k.
// Verified fragment layouts (learn_hip m89/m91):
//   A/B operand: lane holds [row = lane&15][k = (lane>>4)*8 + j], j=0..7
//   C/D:         col = lane&15, row = (lane>>4)*4 + reg
// ---------------------------------------------------------------------------
__device__ __forceinline__ void gemm_bt_core(
    const bf16* __restrict__ Abase, int lda,
    const bf16* __restrict__ Bbase, int ldb,
    int kIters, f32x4 (&acc)[4][4])
{
  alignas(16) __shared__ bf16 As[128 * 32];
  alignas(16) __shared__ bf16 Bs[128 * 32];
  const int t    = threadIdx.x;
  const int lane = t & 63;
  const int quad = lane >> 4, r16 = lane & 15;
  const int wave = t >> 6;
  const int wm = (wave & 1) * 64, wn = (wave >> 1) * 64;
  const int srow = t >> 2;        // staging row 0..63 (and +64)
  const int soff = (t & 3) * 8;   // staging k-offset (elems)

#pragma unroll
  for (int i = 0; i < 4; i++)
#pragma unroll
    for (int j = 0; j < 4; j++) acc[i][j] = {0.f, 0.f, 0.f, 0.f};

  for (int ks = 0; ks < kIters; ++ks) {
    const int k0 = ks * 32;
    const bf16* ap = Abase + (long)srow * lda + k0 + soff;
    const bf16* bp = Bbase + (long)srow * ldb + k0 + soff;
    int4v a0 = *(const int4v*)ap;
    int4v a1 = *(const int4v*)(ap + 64l * lda);
    int4v b0 = *(const int4v*)bp;
    int4v b1 = *(const int4v*)(bp + 64l * ldb);
    __syncthreads();  // previous iteration's LDS reads done before overwrite
    *(int4v*)&As[srow * 32 + soff]        = a0;
    *(int4v*)&As[(srow + 64) * 32 + soff] = a1;
    *(int4v*)&Bs[srow * 32 + soff]        = b0;
    *(int4v*)&Bs[(srow + 64) * 32 + soff] = b1;
    __syncthreads();
    bf16x8 af[4], bfr[4];
#pragma unroll
    for (int i = 0; i < 4; i++)
      af[i] = *(const bf16x8*)&As[(wm + i * 16 + r16) * 32 + quad * 8];
#pragma unroll
    for (int j = 0; j < 4; j++)
      bfr[j] = *(const bf16x8*)&Bs[(wn + j * 16 + r16) * 32 + quad * 8];
#pragma unroll
    for (int i = 0; i < 4; i++)
#pragma unroll
      for (int j = 0; j < 4; j++)
        acc[i][j] = __builtin_amdgcn_mfma_f32_16x16x32_bf16(af[i], bfr[j], acc[i][j], 0, 0, 0);
  }
}

__device__ __forceinline__ void store_bf16_tile(
    f32x4 (&acc)[4][4], bf16* __restrict__ Cp, int ldc)
{
  const int t = threadIdx.x;
  const int lane = t & 63;
  const int quad = lane >> 4, r16 = lane & 15;
  const int wave = t >> 6;
  const int wm = (wave & 1) * 64, wn = (wave >> 1) * 64;
#pragma unroll
  for (int i = 0; i < 4; i++)
#pragma unroll
    for (int j = 0; j < 4; j++)
#pragma unroll
      for (int r = 0; r < 4; r++) {
        const int row = wm + i * 16 + quad * 4 + r;
        const int col = wn + j * 16 + r16;
        Cp[(long)row * ldc + col] = __float2bfloat16(acc[i][j][r]);
      }
}

__device__ __forceinline__ void store_f32_tile(
    f32x4 (&acc)[4][4], float* __restrict__ Cp, int ldc)
{
  const int t = threadIdx.x;
  const int lane = t & 63;
  const int quad = lane >> 4, r16 = lane & 15;
  const int wave = t >> 6;
  const int wm = (wave & 1) * 64, wn = (wave >> 1) * 64;
#pragma unroll
  for (int i = 0; i < 4; i++)
#pragma unroll
    for (int j = 0; j < 4; j++)
#pragma unroll
      for (int r = 0; r < 4; r++) {
        const int row = wm + i * 16 + quad * 4 + r;
        const int col = wn + j * 16 + r16;
        Cp[(long)row * ldc + col] = acc[i][j][r];
      }
}

// ---- elementwise f32 -> bf16 convert (weights) ----
__global__ __launch_bounds__(256) void k_cvt_bf16(
    const float* __restrict__ in, bf16* __restrict__ out)
{
  const long i = (long)blockIdx.x * 256 + threadIdx.x;
  out[i] = __float2bfloat16(in[i]);
}

__global__ void k_zero_f32(float* __restrict__ p)
{
  p[(long)blockIdx.x * 256 + threadIdx.x] = 0.f;
}

__global__ void k_scale_m(const float* __restrict__ Mf, bf16* __restrict__ Mb)
{
  const long i = (long)blockIdx.x * 256 + threadIdx.x;
  Mb[i] = __float2bfloat16(Mf[i] * SCALE);
}

// ---- transpose+convert: f32 (1024 x 2048) -> bf16 (2048 x 1024) per z ----
__global__ __launch_bounds__(256) void k_transpose_cvt(
    const float* __restrict__ in, bf16* __restrict__ out, long inZ, long outZ)
{
  __shared__ bf16 tile[32][33];
  const float* ip = in + (long)blockIdx.z * inZ;
  bf16* op = out + (long)blockIdx.z * outZ;
  const int c0 = blockIdx.x * 32, r0 = blockIdx.y * 32;
  const int tx = threadIdx.x & 31, ty = threadIdx.x >> 5;  // 32 x 8
#pragma unroll
  for (int i = 0; i < 32; i += 8)
    tile[ty + i][tx] = __float2bfloat16(ip[(long)(r0 + ty + i) * 2048 + c0 + tx]);
  __syncthreads();
#pragma unroll
  for (int i = 0; i < 32; i += 8)
    op[(long)(c0 + ty + i) * 1024 + r0 + tx] = tile[tx][ty + i];
}

// ---- transpose bf16 (1024 x 2048 slice) -> bf16 (2048 x 1024) per z ----
__global__ __launch_bounds__(256) void k_transpose_bf16(
    const bf16* __restrict__ in, bf16* __restrict__ out, long inZ, long outZ)
{
  __shared__ bf16 tile[32][33];
  const bf16* ip = in + (long)blockIdx.z * inZ;
  bf16* op = out + (long)blockIdx.z * outZ;
  const int c0 = blockIdx.x * 32, r0 = blockIdx.y * 32;
  const int tx = threadIdx.x & 31, ty = threadIdx.x >> 5;
#pragma unroll
  for (int i = 0; i < 32; i += 8)
    tile[ty + i][tx] = ip[(long)(r0 + ty + i) * 2048 + c0 + tx];
  __syncthreads();
#pragma unroll
  for (int i = 0; i < 32; i += 8)
    op[(long)(c0 + ty + i) * 1024 + r0 + tx] = tile[tx][ty + i];
}

// ---- qkv[b] = W_qkv(3072x1024) . xT[b](2048x1024)^T -> bf16 (3072x2048) ----
__global__ __launch_bounds__(256) void k_gemm_qkv(
    const bf16* __restrict__ Wqkv, const bf16* __restrict__ xT, bf16* __restrict__ qkv)
{
  const int m0 = blockIdx.x * 128, n0 = blockIdx.y * 128, b = blockIdx.z;
  f32x4 acc[4][4];
  gemm_bt_core(Wqkv + (long)m0 * Cn, Cn,
               xT + (long)b * S * Cn + (long)n0 * Cn, Cn, Cn / 32, acc);
  store_bf16_tile(acc, qkv + (long)b * O3 * S + (long)m0 * S + n0, S);
}

// ---- M[b,h](128x128) += V_h . K_h^T over a 128-wide s-chunk (f32 atomic) ----
__global__ __launch_bounds__(256) void k_gemm_m(
    const bf16* __restrict__ qkv, float* __restrict__ Mf)
{
  const int chunk = blockIdx.x;               // 16 chunks of 128 along s
  const int z = blockIdx.y;                   // b*8 + h
  const int b = z >> 3, h = z & 7;
  const bf16* base = qkv + (long)b * O3 * S;
  const bf16* A  = base + (long)(2 * Cn + h * Dh) * S + chunk * 128;  // V rows
  const bf16* Bp = base + (long)(Cn + h * Dh) * S + chunk * 128;      // K rows
  f32x4 acc[4][4];
  gemm_bt_core(A, S, Bp, S, 4, acc);
  float* Mp = Mf + (long)z * Dh * Dh;
  const int t = threadIdx.x;
  const int lane = t & 63;
  const int quad = lane >> 4, r16 = lane & 15;
  const int wave = t >> 6;
  const int wm = (wave & 1) * 64, wn = (wave >> 1) * 64;
#pragma unroll
  for (int i = 0; i < 4; i++)
#pragma unroll
    for (int j = 0; j < 4; j++)
#pragma unroll
      for (int r = 0; r < 4; r++) {
        const int row = wm + i * 16 + quad * 4 + r;
        const int col = wn + j * 16 + r16;
        atomicAdd(&Mp[row * Dh + col], acc[i][j][r]);
      }
}

// ---- CT[b][s][h*128+d] = sum_e QT[b][s][h*128+e] * Mb[b,h][d][e] ----
__global__ __launch_bounds__(256) void k_gemm_ct(
    const bf16* __restrict__ QT, const bf16* __restrict__ Mb, bf16* __restrict__ CT)
{
  const int m0 = blockIdx.x * 128;  // s tile
  const int z = blockIdx.y;
  const int b = z >> 3, h = z & 7;
  f32x4 acc[4][4];
  gemm_bt_core(QT + (long)b * S * Cn + (long)m0 * Cn + h * Dh, Cn,
               Mb + (long)z * Dh * Dh, Dh, 4, acc);
  store_bf16_tile(acc, CT + (long)b * S * Cn + (long)m0 * Cn + h * Dh, Cn);
}

// ---- out[b][o][s] = sum_c W_out[o][c] * CT[b][s][c] -> f32 final ----
__global__ __launch_bounds__(256) void k_gemm_out(
    const bf16* __restrict__ Wout, const bf16* __restrict__ CT, float* __restrict__ out)
{
  const int m0 = blockIdx.x * 128, n0 = blockIdx.y * 128, b = blockIdx.z;
  f32x4 acc[4][4];
  gemm_bt_core(Wout + (long)m0 * Cn, Cn,
               CT + (long)b * S * Cn + (long)n0 * Cn, Cn, Cn / 32, acc);
  store_f32_tile(acc, out + (long)b * Cn * S + (long)m0 * S + n0, S);
}

extern "C" void kernel_launch(void* const* d_in, const int* in_sizes, int n_in,
                              void* d_out, int out_size, void* d_ws, size_t ws_size,
                              hipStream_t stream)
{
  const float* x    = (const float*)d_in[0];  // (4,1024,2048) f32
  const float* Wqkv = (const float*)d_in[1];  // (3072,1024)   f32
  const float* Wout = (const float*)d_in[2];  // (1024,1024)   f32
  float* out = (float*)d_out;                 // (4,1024,2048) f32

  char* ws = (char*)d_ws;
  bf16*  qkv   = (bf16*)ws;                      // 50,331,648 B
  bf16*  xT    = (bf16*)(ws + 50331648);         // 16,777,216 B (reused as QT)
  bf16*  CT    = (bf16*)(ws + 67108864);         // 16,777,216 B
  bf16*  WqkvB = (bf16*)(ws + 83886080);         //  6,291,456 B
  bf16*  WoutB = (bf16*)(ws + 90177536);         //  2,097,152 B
  float* Mf    = (float*)(ws + 92274688);        //  2,097,152 B
  bf16*  Mb    = (bf16*)(ws + 94371840);         //  1,048,576 B (end ~91 MB)

  // convert weights f32 -> bf16
  k_cvt_bf16<<<dim3(12288), 256, 0, stream>>>(Wqkv, WqkvB);
  k_cvt_bf16<<<dim3(4096), 256, 0, stream>>>(Wout, WoutB);
  // zero M accumulator (ws is poisoned 0xAA each call)
  k_zero_f32<<<dim3(2048), 256, 0, stream>>>(Mf);
  // xT[b] = bf16(x[b]^T)
  k_transpose_cvt<<<dim3(64, 32, 4), 256, 0, stream>>>(
      x, xT, (long)1024 * 2048, (long)2048 * 1024);
  // qkv[b] = W_qkv . x[b]
  k_gemm_qkv<<<dim3(24, 16, 4), 256, 0, stream>>>(WqkvB, xT, qkv);
  // QT[b] = Q[b]^T (first 1024 rows of qkv[b]); reuses xT buffer
  k_transpose_bf16<<<dim3(64, 32, 4), 256, 0, stream>>>(
      qkv, xT, (long)3072 * 2048, (long)2048 * 1024);
  // M[b,h] = V_h . K_h^T (s split into 16 chunks, f32 atomic accumulate)
  k_gemm_m<<<dim3(16, 32), 256, 0, stream>>>(qkv, Mf);
  // Mb = bf16(SCALE * M)
  k_scale_m<<<dim3(2048), 256, 0, stream>>>(Mf, Mb);
  // CT[b][s][c] = (M_h . Q_h)^T, scale folded into Mb
  k_gemm_ct<<<dim3(16, 32), 256, 0, stream>>>(xT /*QT*/, Mb, CT);
  // out[b] = W_out . C[b]  (f32 output)
  k_gemm_out<<<dim3(8, 16, 4), 256, 0, stream>>>(WoutB, CT, out);
}

// Round 3
// 251.848 us; speedup vs baseline: 1.0193x; 1.0193x over previous
//
#include <hip/hip_runtime.h>
#include <hip/hip_bf16.h>
#include <stdint.h>

using bf16 = __hip_bfloat16;

typedef __bf16 bf16x8 __attribute__((ext_vector_type(8)));
typedef float  f32x4  __attribute__((ext_vector_type(4)));

constexpr int Bc = 4, Hh = 8, Dh = 128, S = 2048, Cn = 1024, O3 = 3072;
constexpr float SCALE = 0.08838834764831845f;  // 1/sqrt(128)

// async global->LDS, 16B per lane, wave-uniform LDS base + lane*16 scatter
#define GLDS16(gp, lp)                                               \
  __builtin_amdgcn_global_load_lds(                                  \
      (const __attribute__((address_space(1))) void*)(gp),           \
      (__attribute__((address_space(3))) void*)(lp), 16, 0, 0)

// ---------------------------------------------------------------------------
// BT-GEMM core (m97 structure): acc[m][n] += sum_k A[m][k] * B[n][k]
// 128x128 output tile, 256 threads = 4 waves, each wave a 64x64 quadrant
// (4x4 tiles of 16x16x32 MFMA). A,B row-major, contiguous in k.
// Staging: per wave, rows [w*32, w*32+32) of As and Bs via 4x global_load_lds
// wave-loads (1KB each: lane i -> row i/4, k-elems (i%4)*8).
// Fragment layouts (learn_hip m89/m91):
//   A/B operand: lane holds [row = lane&15][k = (lane>>4)*8 + j], j=0..7
//   C/D:         col = lane&15, row = (lane>>4)*4 + reg
// ---------------------------------------------------------------------------
__device__ __forceinline__ void gemm_bt_core(
    const bf16* __restrict__ Abase, int lda,
    const bf16* __restrict__ Bbase, int ldb,
    int kIters, f32x4 (&acc)[4][4])
{
  alignas(16) __shared__ bf16 As[128 * 32];
  alignas(16) __shared__ bf16 Bs[128 * 32];
  const int t    = threadIdx.x;
  const int lane = t & 63;
  const int quad = lane >> 4, r16 = lane & 15;
  const int wave = t >> 6;
  const int wm = (wave & 1) * 64, wn = (wave >> 1) * 64;
  const int lrow = lane >> 2;        // 0..15 within a 16-row chunk
  const int lk   = (lane & 3) * 8;   // k-offset (elems)

  // per-lane global element offsets for the two 16-row chunks of this wave
  const long aOff0 = (long)(wave * 32 + lrow) * lda + lk;
  const long aOff1 = aOff0 + 16l * lda;
  const long bOff0 = (long)(wave * 32 + lrow) * ldb + lk;
  const long bOff1 = bOff0 + 16l * ldb;
  // wave-uniform LDS chunk bases
  bf16* aL0 = &As[(wave * 32) * 32];
  bf16* aL1 = &As[(wave * 32 + 16) * 32];
  bf16* bL0 = &Bs[(wave * 32) * 32];
  bf16* bL1 = &Bs[(wave * 32 + 16) * 32];

#pragma unroll
  for (int i = 0; i < 4; i++)
#pragma unroll
    for (int j = 0; j < 4; j++) acc[i][j] = {0.f, 0.f, 0.f, 0.f};

  for (int ks = 0; ks < kIters; ++ks) {
    const int k0 = ks * 32;
    __syncthreads();  // all waves done reading LDS from previous iter
    GLDS16(Abase + k0 + aOff0, aL0);
    GLDS16(Abase + k0 + aOff1, aL1);
    GLDS16(Bbase + k0 + bOff0, bL0);
    GLDS16(Bbase + k0 + bOff1, bL1);
    __syncthreads();  // drains vmcnt(0): DMA'd data visible to all waves
    bf16x8 af[4], bfr[4];
#pragma unroll
    for (int i = 0; i < 4; i++)
      af[i] = *(const bf16x8*)&As[(wm + i * 16 + r16) * 32 + quad * 8];
#pragma unroll
    for (int j = 0; j < 4; j++)
      bfr[j] = *(const bf16x8*)&Bs[(wn + j * 16 + r16) * 32 + quad * 8];
#pragma unroll
    for (int i = 0; i < 4; i++)
#pragma unroll
      for (int j = 0; j < 4; j++)
        acc[i][j] = __builtin_amdgcn_mfma_f32_16x16x32_bf16(af[i], bfr[j], acc[i][j], 0, 0, 0);
  }
}

__device__ __forceinline__ void store_bf16_tile(
    f32x4 (&acc)[4][4], bf16* __restrict__ Cp, int ldc)
{
  const int t = threadIdx.x;
  const int lane = t & 63;
  const int quad = lane >> 4, r16 = lane & 15;
  const int wave = t >> 6;
  const int wm = (wave & 1) * 64, wn = (wave >> 1) * 64;
#pragma unroll
  for (int i = 0; i < 4; i++)
#pragma unroll
    for (int j = 0; j < 4; j++)
#pragma unroll
      for (int r = 0; r < 4; r++) {
        const int row = wm + i * 16 + quad * 4 + r;
        const int col = wn + j * 16 + r16;
        Cp[(long)row * ldc + col] = __float2bfloat16(acc[i][j][r]);
      }
}

__device__ __forceinline__ void store_f32_tile(
    f32x4 (&acc)[4][4], float* __restrict__ Cp, int ldc)
{
  const int t = threadIdx.x;
  const int lane = t & 63;
  const int quad = lane >> 4, r16 = lane & 15;
  const int wave = t >> 6;
  const int wm = (wave & 1) * 64, wn = (wave >> 1) * 64;
#pragma unroll
  for (int i = 0; i < 4; i++)
#pragma unroll
    for (int j = 0; j < 4; j++)
#pragma unroll
      for (int r = 0; r < 4; r++) {
        const int row = wm + i * 16 + quad * 4 + r;
        const int col = wn + j * 16 + r16;
        Cp[(long)row * ldc + col] = acc[i][j][r];
      }
}

// ---- elementwise f32 -> bf16 convert (weights) ----
__global__ __launch_bounds__(256) void k_cvt_bf16(
    const float* __restrict__ in, bf16* __restrict__ out)
{
  const long i = (long)blockIdx.x * 256 + threadIdx.x;
  out[i] = __float2bfloat16(in[i]);
}

__global__ void k_zero_f32(float* __restrict__ p)
{
  p[(long)blockIdx.x * 256 + threadIdx.x] = 0.f;
}

__global__ void k_scale_m(const float* __restrict__ Mf, bf16* __restrict__ Mb)
{
  const long i = (long)blockIdx.x * 256 + threadIdx.x;
  Mb[i] = __float2bfloat16(Mf[i] * SCALE);
}

// ---- transpose+convert: f32 (1024 x 2048) -> bf16 (2048 x 1024) per z ----
__global__ __launch_bounds__(256) void k_transpose_cvt(
    const float* __restrict__ in, bf16* __restrict__ out, long inZ, long outZ)
{
  __shared__ bf16 tile[32][33];
  const float* ip = in + (long)blockIdx.z * inZ;
  bf16* op = out + (long)blockIdx.z * outZ;
  const int c0 = blockIdx.x * 32, r0 = blockIdx.y * 32;
  const int tx = threadIdx.x & 31, ty = threadIdx.x >> 5;  // 32 x 8
#pragma unroll
  for (int i = 0; i < 32; i += 8)
    tile[ty + i][tx] = __float2bfloat16(ip[(long)(r0 + ty + i) * 2048 + c0 + tx]);
  __syncthreads();
#pragma unroll
  for (int i = 0; i < 32; i += 8)
    op[(long)(c0 + ty + i) * 1024 + r0 + tx] = tile[tx][ty + i];
}

// ---- transpose bf16 (1024 x 2048 slice) -> bf16 (2048 x 1024) per z ----
__global__ __launch_bounds__(256) void k_transpose_bf16(
    const bf16* __restrict__ in, bf16* __restrict__ out, long inZ, long outZ)
{
  __shared__ bf16 tile[32][33];
  const bf16* ip = in + (long)blockIdx.z * inZ;
  bf16* op = out + (long)blockIdx.z * outZ;
  const int c0 = blockIdx.x * 32, r0 = blockIdx.y * 32;
  const int tx = threadIdx.x & 31, ty = threadIdx.x >> 5;
#pragma unroll
  for (int i = 0; i < 32; i += 8)
    tile[ty + i][tx] = ip[(long)(r0 + ty + i) * 2048 + c0 + tx];
  __syncthreads();
#pragma unroll
  for (int i = 0; i < 32; i += 8)
    op[(long)(c0 + ty + i) * 1024 + r0 + tx] = tile[tx][ty + i];
}

// ---- qkv[b] = W_qkv(3072x1024) . xT[b](2048x1024)^T -> bf16 (3072x2048) ----
__global__ __launch_bounds__(256) void k_gemm_qkv(
    const bf16* __restrict__ Wqkv, const bf16* __restrict__ xT, bf16* __restrict__ qkv)
{
  const int m0 = blockIdx.x * 128, n0 = blockIdx.y * 128, b = blockIdx.z;
  f32x4 acc[4][4];
  gemm_bt_core(Wqkv + (long)m0 * Cn, Cn,
               xT + (long)b * S * Cn + (long)n0 * Cn, Cn, Cn / 32, acc);
  store_bf16_tile(acc, qkv + (long)b * O3 * S + (long)m0 * S + n0, S);
}

// ---- M[b,h](128x128) += V_h . K_h^T over a 128-wide s-chunk (f32 atomic) ----
__global__ __launch_bounds__(256) void k_gemm_m(
    const bf16* __restrict__ qkv, float* __restrict__ Mf)
{
  const int chunk = blockIdx.x;               // 16 chunks of 128 along s
  const int z = blockIdx.y;                   // b*8 + h
  const int b = z >> 3, h = z & 7;
  const bf16* base = qkv + (long)b * O3 * S;
  const bf16* A  = base + (long)(2 * Cn + h * Dh) * S + chunk * 128;  // V rows
  const bf16* Bp = base + (long)(Cn + h * Dh) * S + chunk * 128;      // K rows
  f32x4 acc[4][4];
  gemm_bt_core(A, S, Bp, S, 4, acc);
  float* Mp = Mf + (long)z * Dh * Dh;
  const int t = threadIdx.x;
  const int lane = t & 63;
  const int quad = lane >> 4, r16 = lane & 15;
  const int wave = t >> 6;
  const int wm = (wave & 1) * 64, wn = (wave >> 1) * 64;
#pragma unroll
  for (int i = 0; i < 4; i++)
#pragma unroll
    for (int j = 0; j < 4; j++)
#pragma unroll
      for (int r = 0; r < 4; r++) {
        const int row = wm + i * 16 + quad * 4 + r;
        const int col = wn + j * 16 + r16;
        atomicAdd(&Mp[row * Dh + col], acc[i][j][r]);
      }
}

// ---- CT[b][s][h*128+d] = sum_e QT[b][s][h*128+e] * Mb[b,h][d][e] ----
__global__ __launch_bounds__(256) void k_gemm_ct(
    const bf16* __restrict__ QT, const bf16* __restrict__ Mb, bf16* __restrict__ CT)
{
  const int m0 = blockIdx.x * 128;  // s tile
  const int z = blockIdx.y;
  const int b = z >> 3, h = z & 7;
  f32x4 acc[4][4];
  gemm_bt_core(QT + (long)b * S * Cn + (long)m0 * Cn + h * Dh, Cn,
               Mb + (long)z * Dh * Dh, Dh, 4, acc);
  store_bf16_tile(acc, CT + (long)b * S * Cn + (long)m0 * Cn + h * Dh, Cn);
}

// ---- out[b][o][s] = sum_c W_out[o][c] * CT[b][s][c] -> f32 final ----
__global__ __launch_bounds__(256) void k_gemm_out(
    const bf16* __restrict__ Wout, const bf16* __restrict__ CT, float* __restrict__ out)
{
  const int m0 = blockIdx.x * 128, n0 = blockIdx.y * 128, b = blockIdx.z;
  f32x4 acc[4][4];
  gemm_bt_core(Wout + (long)m0 * Cn, Cn,
               CT + (long)b * S * Cn + (long)n0 * Cn, Cn, Cn / 32, acc);
  store_f32_tile(acc, out + (long)b * Cn * S + (long)m0 * S + n0, S);
}

extern "C" void kernel_launch(void* const* d_in, const int* in_sizes, int n_in,
                              void* d_out, int out_size, void* d_ws, size_t ws_size,
                              hipStream_t stream)
{
  const float* x    = (const float*)d_in[0];  // (4,1024,2048) f32
  const float* Wqkv = (const float*)d_in[1];  // (3072,1024)   f32
  const float* Wout = (const float*)d_in[2];  // (1024,1024)   f32
  float* out = (float*)d_out;                 // (4,1024,2048) f32

  char* ws = (char*)d_ws;
  bf16*  qkv   = (bf16*)ws;                      // 50,331,648 B
  bf16*  xT    = (bf16*)(ws + 50331648);         // 16,777,216 B (reused as QT)
  bf16*  CT    = (bf16*)(ws + 67108864);         // 16,777,216 B
  bf16*  WqkvB = (bf16*)(ws + 83886080);         //  6,291,456 B
  bf16*  WoutB = (bf16*)(ws + 90177536);         //  2,097,152 B
  float* Mf    = (float*)(ws + 92274688);        //  2,097,152 B
  bf16*  Mb    = (bf16*)(ws + 94371840);         //  1,048,576 B (end ~91 MB)

  // convert weights f32 -> bf16
  k_cvt_bf16<<<dim3(12288), 256, 0, stream>>>(Wqkv, WqkvB);
  k_cvt_bf16<<<dim3(4096), 256, 0, stream>>>(Wout, WoutB);
  // zero M accumulator (ws is poisoned 0xAA each call)
  k_zero_f32<<<dim3(2048), 256, 0, stream>>>(Mf);
  // xT[b] = bf16(x[b]^T)
  k_transpose_cvt<<<dim3(64, 32, 4), 256, 0, stream>>>(
      x, xT, (long)1024 * 2048, (long)2048 * 1024);
  // qkv[b] = W_qkv . x[b]
  k_gemm_qkv<<<dim3(24, 16, 4), 256, 0, stream>>>(WqkvB, xT, qkv);
  // QT[b] = Q[b]^T (first 1024 rows of qkv[b]); reuses xT buffer
  k_transpose_bf16<<<dim3(64, 32, 4), 256, 0, stream>>>(
      qkv, xT, (long)3072 * 2048, (long)2048 * 1024);
  // M[b,h] = V_h . K_h^T (s split into 16 chunks, f32 atomic accumulate)
  k_gemm_m<<<dim3(16, 32), 256, 0, stream>>>(qkv, Mf);
  // Mb = bf16(SCALE * M)
  k_scale_m<<<dim3(2048), 256, 0, stream>>>(Mf, Mb);
  // CT[b][s][c] = (M_h . Q_h)^T, scale folded into Mb
  k_gemm_ct<<<dim3(16, 32), 256, 0, stream>>>(xT /*QT*/, Mb, CT);
  // out[b] = W_out . C[b]  (f32 output)
  k_gemm_out<<<dim3(8, 16, 4), 256, 0, stream>>>(WoutB, CT, out);
}

// Round 4
// 222.503 us; speedup vs baseline: 1.1537x; 1.1319x over previous
//
#include <hip/hip_runtime.h>
#include <hip/hip_bf16.h>
#include <stdint.h>

using bf16 = __hip_bfloat16;

typedef __bf16 bf16x8 __attribute__((ext_vector_type(8)));
typedef float  f32x4  __attribute__((ext_vector_type(4)));

constexpr int Bc = 4, Hh = 8, Dh = 128, S = 2048, Cn = 1024, O3 = 3072;
constexpr float SCALE = 0.08838834764831845f;  // 1/sqrt(128)

// async global->LDS, 16B per lane, wave-uniform LDS base + lane*16 scatter
#define GLDS16(gp, lp)                                               \
  __builtin_amdgcn_global_load_lds(                                  \
      (const __attribute__((address_space(1))) void*)(gp),           \
      (__attribute__((address_space(3))) void*)(lp), 16, 0, 0)

// ---------------------------------------------------------------------------
// BT-GEMM core (m97 structure): acc[m][n] += sum_k A[m][k] * B[n][k]
// 128x128 output tile, 256 threads = 4 waves, each wave a 64x64 quadrant
// (4x4 tiles of 16x16x32 MFMA). A,B row-major, contiguous in k.
// ---------------------------------------------------------------------------
__device__ __forceinline__ void gemm_bt_core(
    const bf16* __restrict__ Abase, int lda,
    const bf16* __restrict__ Bbase, int ldb,
    int kIters, f32x4 (&acc)[4][4])
{
  alignas(16) __shared__ bf16 As[128 * 32];
  alignas(16) __shared__ bf16 Bs[128 * 32];
  const int t    = threadIdx.x;
  const int lane = t & 63;
  const int quad = lane >> 4, r16 = lane & 15;
  const int wave = t >> 6;
  const int wm = (wave & 1) * 64, wn = (wave >> 1) * 64;
  const int lrow = lane >> 2;        // 0..15 within a 16-row chunk
  const int lk   = (lane & 3) * 8;   // k-offset (elems)

  const long aOff0 = (long)(wave * 32 + lrow) * lda + lk;
  const long aOff1 = aOff0 + 16l * lda;
  const long bOff0 = (long)(wave * 32 + lrow) * ldb + lk;
  const long bOff1 = bOff0 + 16l * ldb;
  bf16* aL0 = &As[(wave * 32) * 32];
  bf16* aL1 = &As[(wave * 32 + 16) * 32];
  bf16* bL0 = &Bs[(wave * 32) * 32];
  bf16* bL1 = &Bs[(wave * 32 + 16) * 32];

#pragma unroll
  for (int i = 0; i < 4; i++)
#pragma unroll
    for (int j = 0; j < 4; j++) acc[i][j] = {0.f, 0.f, 0.f, 0.f};

  for (int ks = 0; ks < kIters; ++ks) {
    const int k0 = ks * 32;
    __syncthreads();  // all waves done reading LDS from previous iter
    GLDS16(Abase + k0 + aOff0, aL0);
    GLDS16(Abase + k0 + aOff1, aL1);
    GLDS16(Bbase + k0 + bOff0, bL0);
    GLDS16(Bbase + k0 + bOff1, bL1);
    __syncthreads();  // drains vmcnt(0): DMA'd data visible to all waves
    bf16x8 af[4], bfr[4];
#pragma unroll
    for (int i = 0; i < 4; i++)
      af[i] = *(const bf16x8*)&As[(wm + i * 16 + r16) * 32 + quad * 8];
#pragma unroll
    for (int j = 0; j < 4; j++)
      bfr[j] = *(const bf16x8*)&Bs[(wn + j * 16 + r16) * 32 + quad * 8];
#pragma unroll
    for (int i = 0; i < 4; i++)
#pragma unroll
      for (int j = 0; j < 4; j++)
        acc[i][j] = __builtin_amdgcn_mfma_f32_16x16x32_bf16(af[i], bfr[j], acc[i][j], 0, 0, 0);
  }
}

__device__ __forceinline__ void store_bf16_tile(
    f32x4 (&acc)[4][4], bf16* __restrict__ Cp, int ldc)
{
  const int t = threadIdx.x;
  const int lane = t & 63;
  const int quad = lane >> 4, r16 = lane & 15;
  const int wave = t >> 6;
  const int wm = (wave & 1) * 64, wn = (wave >> 1) * 64;
#pragma unroll
  for (int i = 0; i < 4; i++)
#pragma unroll
    for (int j = 0; j < 4; j++)
#pragma unroll
      for (int r = 0; r < 4; r++) {
        const int row = wm + i * 16 + quad * 4 + r;
        const int col = wn + j * 16 + r16;
        Cp[(long)row * ldc + col] = __float2bfloat16(acc[i][j][r]);
      }
}

__device__ __forceinline__ void store_f32_tile(
    f32x4 (&acc)[4][4], float* __restrict__ Cp, int ldc)
{
  const int t = threadIdx.x;
  const int lane = t & 63;
  const int quad = lane >> 4, r16 = lane & 15;
  const int wave = t >> 6;
  const int wm = (wave & 1) * 64, wn = (wave >> 1) * 64;
#pragma unroll
  for (int i = 0; i < 4; i++)
#pragma unroll
    for (int j = 0; j < 4; j++)
#pragma unroll
      for (int r = 0; r < 4; r++) {
        const int row = wm + i * 16 + quad * 4 + r;
        const int col = wn + j * 16 + r16;
        Cp[(long)row * ldc + col] = acc[i][j][r];
      }
}

// ---- elementwise f32 -> bf16 convert (weights) ----
__global__ __launch_bounds__(256) void k_cvt_bf16(
    const float* __restrict__ in, bf16* __restrict__ out)
{
  const long i = (long)blockIdx.x * 256 + threadIdx.x;
  out[i] = __float2bfloat16(in[i]);
}

// ---- transpose+convert: f32 (1024 x 2048) -> bf16 (2048 x 1024) per z ----
__global__ __launch_bounds__(256) void k_transpose_cvt(
    const float* __restrict__ in, bf16* __restrict__ out, long inZ, long outZ)
{
  __shared__ bf16 tile[32][33];
  const float* ip = in + (long)blockIdx.z * inZ;
  bf16* op = out + (long)blockIdx.z * outZ;
  const int c0 = blockIdx.x * 32, r0 = blockIdx.y * 32;
  const int tx = threadIdx.x & 31, ty = threadIdx.x >> 5;  // 32 x 8
#pragma unroll
  for (int i = 0; i < 32; i += 8)
    tile[ty + i][tx] = __float2bfloat16(ip[(long)(r0 + ty + i) * 2048 + c0 + tx]);
  __syncthreads();
#pragma unroll
  for (int i = 0; i < 32; i += 8)
    op[(long)(c0 + ty + i) * 1024 + r0 + tx] = tile[tx][ty + i];
}

// ---- transpose bf16 (1024 x 2048 slice) -> bf16 (2048 x 1024) per z ----
__global__ __launch_bounds__(256) void k_transpose_bf16(
    const bf16* __restrict__ in, bf16* __restrict__ out, long inZ, long outZ)
{
  __shared__ bf16 tile[32][33];
  const bf16* ip = in + (long)blockIdx.z * inZ;
  bf16* op = out + (long)blockIdx.z * outZ;
  const int c0 = blockIdx.x * 32, r0 = blockIdx.y * 32;
  const int tx = threadIdx.x & 31, ty = threadIdx.x >> 5;
#pragma unroll
  for (int i = 0; i < 32; i += 8)
    tile[ty + i][tx] = ip[(long)(r0 + ty + i) * 2048 + c0 + tx];
  __syncthreads();
#pragma unroll
  for (int i = 0; i < 32; i += 8)
    op[(long)(c0 + ty + i) * 1024 + r0 + tx] = tile[tx][ty + i];
}

// ---- qkv[b] = W_qkv(3072x1024) . xT[b](2048x1024)^T -> bf16 (3072x2048) ----
__global__ __launch_bounds__(256) void k_gemm_qkv(
    const bf16* __restrict__ Wqkv, const bf16* __restrict__ xT, bf16* __restrict__ qkv)
{
  const int m0 = blockIdx.x * 128, n0 = blockIdx.y * 128, b = blockIdx.z;
  f32x4 acc[4][4];
  gemm_bt_core(Wqkv + (long)m0 * Cn, Cn,
               xT + (long)b * S * Cn + (long)n0 * Cn, Cn, Cn / 32, acc);
  store_bf16_tile(acc, qkv + (long)b * O3 * S + (long)m0 * S + n0, S);
}

// ---- MTpart[chunk][b,h][e][d] = K_h . V_h^T over a 256-wide s-chunk ----
// (split-K, f32 partials, no atomics)
__global__ __launch_bounds__(256) void k_gemm_mt(
    const bf16* __restrict__ qkv, float* __restrict__ MTpart)
{
  const int chunk = blockIdx.x;               // 8 chunks of 256 along s
  const int z = blockIdx.y;                   // b*8 + h
  const int b = z >> 3, h = z & 7;
  const bf16* base = qkv + (long)b * O3 * S;
  const bf16* A  = base + (long)(Cn + h * Dh) * S + chunk * 256;      // K rows (e)
  const bf16* Bp = base + (long)(2 * Cn + h * Dh) * S + chunk * 256;  // V rows (d)
  f32x4 acc[4][4];
  gemm_bt_core(A, S, Bp, S, 8, acc);
  store_f32_tile(acc, MTpart + ((long)chunk * 32 + z) * (Dh * Dh), Dh);
}

// ---- MbT[z][e][d] = bf16(SCALE * sum_chunk MTpart) ----
__global__ __launch_bounds__(256) void k_reduce_mt(
    const float* __restrict__ MTpart, bf16* __restrict__ MbT)
{
  const long i = (long)blockIdx.x * 256 + threadIdx.x;  // over 32*16384
  float s = 0.f;
#pragma unroll
  for (int c = 0; c < 8; c++) s += MTpart[(long)c * 32 * Dh * Dh + i];
  MbT[i] = __float2bfloat16(s * SCALE);
}

// ---- W2[b][o][h*128+e] = sum_d Wout[o][h*128+d] * MbT[b,h][e][d] ----
__global__ __launch_bounds__(256) void k_gemm_w2(
    const bf16* __restrict__ Wout, const bf16* __restrict__ MbT, bf16* __restrict__ W2)
{
  const int m0 = blockIdx.x * 128;  // o tile
  const int h = blockIdx.y, b = blockIdx.z;
  const int z = b * 8 + h;
  f32x4 acc[4][4];
  gemm_bt_core(Wout + (long)m0 * Cn + h * Dh, Cn,
               MbT + (long)z * Dh * Dh, Dh, 4, acc);
  store_bf16_tile(acc, W2 + (long)b * Cn * Cn + (long)m0 * Cn + h * Dh, Cn);
}

// ---- out[b][o][s] = sum_c W2[b][o][c] * QT[b][s][c] -> f32 final ----
__global__ __launch_bounds__(256) void k_gemm_out(
    const bf16* __restrict__ W2, const bf16* __restrict__ QT, float* __restrict__ out)
{
  const int m0 = blockIdx.x * 128, n0 = blockIdx.y * 128, b = blockIdx.z;
  f32x4 acc[4][4];
  gemm_bt_core(W2 + (long)b * Cn * Cn + (long)m0 * Cn, Cn,
               QT + (long)b * S * Cn + (long)n0 * Cn, Cn, Cn / 32, acc);
  store_f32_tile(acc, out + (long)b * Cn * S + (long)m0 * S + n0, S);
}

extern "C" void kernel_launch(void* const* d_in, const int* in_sizes, int n_in,
                              void* d_out, int out_size, void* d_ws, size_t ws_size,
                              hipStream_t stream)
{
  const float* x    = (const float*)d_in[0];  // (4,1024,2048) f32
  const float* Wqkv = (const float*)d_in[1];  // (3072,1024)   f32
  const float* Wout = (const float*)d_in[2];  // (1024,1024)   f32
  float* out = (float*)d_out;                 // (4,1024,2048) f32

  char* ws = (char*)d_ws;
  bf16*  qkv    = (bf16*)ws;                     // 50,331,648 B
  bf16*  xT     = (bf16*)(ws + 50331648);        // 16,777,216 B (reused as QT)
  float* MTpart = (float*)(ws + 67108864);       // 16,777,216 B (8 x 32 x 64KB)
  bf16*  WoutB  = (bf16*)(ws + 83886080);        //  2,097,152 B
  bf16*  WqkvB  = (bf16*)(ws + 85983232);        //  6,291,456 B (dead after qkv GEMM)
  bf16*  W2     = (bf16*)(ws + 85983232);        //  8,388,608 B (aliases WqkvB)
  bf16*  MbT    = (bf16*)(ws + 94371840);        //  1,048,576 B (end 95,420,416)

  // convert weights f32 -> bf16
  k_cvt_bf16<<<dim3(12288), 256, 0, stream>>>(Wqkv, WqkvB);
  k_cvt_bf16<<<dim3(4096), 256, 0, stream>>>(Wout, WoutB);
  // xT[b] = bf16(x[b]^T)
  k_transpose_cvt<<<dim3(64, 32, 4), 256, 0, stream>>>(
      x, xT, (long)1024 * 2048, (long)2048 * 1024);
  // qkv[b] = W_qkv . x[b]  (o,s layout)
  k_gemm_qkv<<<dim3(24, 16, 4), 256, 0, stream>>>(WqkvB, xT, qkv);
  // QT[b] = Q[b]^T (first 1024 rows of qkv[b]); reuses xT buffer
  k_transpose_bf16<<<dim3(64, 32, 4), 256, 0, stream>>>(
      qkv, xT, (long)3072 * 2048, (long)2048 * 1024);
  // MT partials: K_h . V_h^T over 8 s-chunks (no atomics)
  k_gemm_mt<<<dim3(8, 32), 256, 0, stream>>>(qkv, MTpart);
  // MbT = bf16(SCALE * sum of partials)
  k_reduce_mt<<<dim3(2048), 256, 0, stream>>>(MTpart, MbT);
  // W2[b] = Wout . (scale*M)  folded per-batch output weights
  k_gemm_w2<<<dim3(8, 8, 4), 256, 0, stream>>>(WoutB, MbT, W2);
  // out[b] = W2[b] . Q[b]  (f32 output)
  k_gemm_out<<<dim3(8, 16, 4), 256, 0, stream>>>(W2, xT /*QT*/, out);
}

// Round 5
// 221.784 us; speedup vs baseline: 1.1574x; 1.0032x over previous
//
#include <hip/hip_runtime.h>
#include <hip/hip_bf16.h>
#include <stdint.h>

using bf16 = __hip_bfloat16;

typedef __bf16 bf16x8 __attribute__((ext_vector_type(8)));
typedef float  f32x4  __attribute__((ext_vector_type(4)));

constexpr int Bc = 4, Hh = 8, Dh = 128, S = 2048, Cn = 1024, O3 = 3072;
constexpr float SCALE = 0.08838834764831845f;  // 1/sqrt(128)

// async global->LDS, 16B per lane, wave-uniform LDS base + lane*16 scatter
#define GLDS16(gp, lp)                                               \
  __builtin_amdgcn_global_load_lds(                                  \
      (const __attribute__((address_space(1))) void*)(gp),           \
      (__attribute__((address_space(3))) void*)(lp), 16, 0, 0)

// ---------------------------------------------------------------------------
// BT-GEMM core (m97 structure): acc[m][n] += sum_k A[m][k] * B[n][k]
// 128x128 output tile, 256 threads = 4 waves, each wave a 64x64 quadrant
// (4x4 tiles of 16x16x32 MFMA). A,B row-major, contiguous in k.
// ---------------------------------------------------------------------------
__device__ __forceinline__ void gemm_bt_core(
    const bf16* __restrict__ Abase, int lda,
    const bf16* __restrict__ Bbase, int ldb,
    int kIters, f32x4 (&acc)[4][4])
{
  alignas(16) __shared__ bf16 As[128 * 32];
  alignas(16) __shared__ bf16 Bs[128 * 32];
  const int t    = threadIdx.x;
  const int lane = t & 63;
  const int quad = lane >> 4, r16 = lane & 15;
  const int wave = t >> 6;
  const int wm = (wave & 1) * 64, wn = (wave >> 1) * 64;
  const int lrow = lane >> 2;        // 0..15 within a 16-row chunk
  const int lk   = (lane & 3) * 8;   // k-offset (elems)

  const long aOff0 = (long)(wave * 32 + lrow) * lda + lk;
  const long aOff1 = aOff0 + 16l * lda;
  const long bOff0 = (long)(wave * 32 + lrow) * ldb + lk;
  const long bOff1 = bOff0 + 16l * ldb;
  bf16* aL0 = &As[(wave * 32) * 32];
  bf16* aL1 = &As[(wave * 32 + 16) * 32];
  bf16* bL0 = &Bs[(wave * 32) * 32];
  bf16* bL1 = &Bs[(wave * 32 + 16) * 32];

#pragma unroll
  for (int i = 0; i < 4; i++)
#pragma unroll
    for (int j = 0; j < 4; j++) acc[i][j] = {0.f, 0.f, 0.f, 0.f};

  for (int ks = 0; ks < kIters; ++ks) {
    const int k0 = ks * 32;
    __syncthreads();  // all waves done reading LDS from previous iter
    GLDS16(Abase + k0 + aOff0, aL0);
    GLDS16(Abase + k0 + aOff1, aL1);
    GLDS16(Bbase + k0 + bOff0, bL0);
    GLDS16(Bbase + k0 + bOff1, bL1);
    __syncthreads();  // drains vmcnt(0): DMA'd data visible to all waves
    bf16x8 af[4], bfr[4];
#pragma unroll
    for (int i = 0; i < 4; i++)
      af[i] = *(const bf16x8*)&As[(wm + i * 16 + r16) * 32 + quad * 8];
#pragma unroll
    for (int j = 0; j < 4; j++)
      bfr[j] = *(const bf16x8*)&Bs[(wn + j * 16 + r16) * 32 + quad * 8];
#pragma unroll
    for (int i = 0; i < 4; i++)
#pragma unroll
      for (int j = 0; j < 4; j++)
        acc[i][j] = __builtin_amdgcn_mfma_f32_16x16x32_bf16(af[i], bfr[j], acc[i][j], 0, 0, 0);
  }
}

__device__ __forceinline__ void store_bf16_tile(
    f32x4 (&acc)[4][4], bf16* __restrict__ Cp, int ldc)
{
  const int t = threadIdx.x;
  const int lane = t & 63;
  const int quad = lane >> 4, r16 = lane & 15;
  const int wave = t >> 6;
  const int wm = (wave & 1) * 64, wn = (wave >> 1) * 64;
#pragma unroll
  for (int i = 0; i < 4; i++)
#pragma unroll
    for (int j = 0; j < 4; j++)
#pragma unroll
      for (int r = 0; r < 4; r++) {
        const int row = wm + i * 16 + quad * 4 + r;
        const int col = wn + j * 16 + r16;
        Cp[(long)row * ldc + col] = __float2bfloat16(acc[i][j][r]);
      }
}

__device__ __forceinline__ void store_f32_tile(
    f32x4 (&acc)[4][4], float* __restrict__ Cp, int ldc)
{
  const int t = threadIdx.x;
  const int lane = t & 63;
  const int quad = lane >> 4, r16 = lane & 15;
  const int wave = t >> 6;
  const int wm = (wave & 1) * 64, wn = (wave >> 1) * 64;
#pragma unroll
  for (int i = 0; i < 4; i++)
#pragma unroll
    for (int j = 0; j < 4; j++)
#pragma unroll
      for (int r = 0; r < 4; r++) {
        const int row = wm + i * 16 + quad * 4 + r;
        const int col = wn + j * 16 + r16;
        Cp[(long)row * ldc + col] = acc[i][j][r];
      }
}

// ---- both weight matrices f32 -> bf16, float4-vectorized, one dispatch ----
__global__ __launch_bounds__(256) void k_cvt_w(
    const float* __restrict__ Wqkv, const float* __restrict__ Wout,
    bf16* __restrict__ WqkvB, bf16* __restrict__ WoutB)
{
  const long v = (long)blockIdx.x * 256 + threadIdx.x;  // vec4 index, 1,048,576 total
  const bool isQ = v < 786432;
  const float4 f = isQ ? ((const float4*)Wqkv)[v] : ((const float4*)Wout)[v - 786432];
  bf16 tmp[4];
  tmp[0] = __float2bfloat16(f.x);
  tmp[1] = __float2bfloat16(f.y);
  tmp[2] = __float2bfloat16(f.z);
  tmp[3] = __float2bfloat16(f.w);
  ushort4 u = *(ushort4*)tmp;
  if (isQ) ((ushort4*)WqkvB)[v] = u;
  else     ((ushort4*)WoutB)[v - 786432] = u;
}

// ---- transpose+convert: f32 (1024 x 2048) -> bf16 (2048 x 1024) per z ----
__global__ __launch_bounds__(256) void k_transpose_cvt(
    const float* __restrict__ in, bf16* __restrict__ out, long inZ, long outZ)
{
  __shared__ bf16 tile[32][33];
  const float* ip = in + (long)blockIdx.z * inZ;
  bf16* op = out + (long)blockIdx.z * outZ;
  const int c0 = blockIdx.x * 32, r0 = blockIdx.y * 32;
  const int tx = threadIdx.x & 31, ty = threadIdx.x >> 5;  // 32 x 8
#pragma unroll
  for (int i = 0; i < 32; i += 8)
    tile[ty + i][tx] = __float2bfloat16(ip[(long)(r0 + ty + i) * 2048 + c0 + tx]);
  __syncthreads();
#pragma unroll
  for (int i = 0; i < 32; i += 8)
    op[(long)(c0 + ty + i) * 1024 + r0 + tx] = tile[tx][ty + i];
}

// ---- QT[b][s][o] = sum_c xT[b][s][c] * Wq[o][c]  (direct, no transpose!) ----
__global__ __launch_bounds__(256) void k_gemm_qT(
    const bf16* __restrict__ xT, const bf16* __restrict__ WqkvB, bf16* __restrict__ QT)
{
  const int m0 = blockIdx.x * 128, n0 = blockIdx.y * 128, b = blockIdx.z;
  f32x4 acc[4][4];
  gemm_bt_core(xT + (long)b * S * Cn + (long)m0 * Cn, Cn,
               WqkvB + (long)n0 * Cn, Cn, Cn / 32, acc);
  store_bf16_tile(acc, QT + (long)b * S * Cn + (long)m0 * Cn + n0, Cn);
}

// ---- KV[b][o'][s] = sum_c Wqkv[1024+o'][c] * x[b][c][s]  (o,s layout) ----
__global__ __launch_bounds__(256) void k_gemm_kv(
    const bf16* __restrict__ WqkvB, const bf16* __restrict__ xT, bf16* __restrict__ KV)
{
  const int m0 = blockIdx.x * 128, n0 = blockIdx.y * 128, b = blockIdx.z;
  f32x4 acc[4][4];
  gemm_bt_core(WqkvB + (long)(Cn + m0) * Cn, Cn,
               xT + (long)b * S * Cn + (long)n0 * Cn, Cn, Cn / 32, acc);
  store_bf16_tile(acc, KV + (long)b * 2048 * S + (long)m0 * S + n0, S);
}

// ---- MTpart[chunk][z][e][d] = K_h . V_h^T over a 256-wide s-chunk ----
__global__ __launch_bounds__(256) void k_gemm_mt(
    const bf16* __restrict__ KV, float* __restrict__ MTpart)
{
  const int chunk = blockIdx.x;               // 8 chunks of 256 along s
  const int z = blockIdx.y;                   // b*8 + h
  const int b = z >> 3, h = z & 7;
  const bf16* base = KV + (long)b * 2048 * S;
  const bf16* A  = base + (long)(h * Dh) * S + chunk * 256;           // K rows (e)
  const bf16* Bp = base + (long)(1024 + h * Dh) * S + chunk * 256;    // V rows (d)
  f32x4 acc[4][4];
  gemm_bt_core(A, S, Bp, S, 8, acc);
  store_f32_tile(acc, MTpart + ((long)chunk * 32 + z) * (Dh * Dh), Dh);
}

// ---- MbT[z][e][d] = bf16(SCALE * sum_chunk MTpart) ----
__global__ __launch_bounds__(256) void k_reduce_mt(
    const float* __restrict__ MTpart, bf16* __restrict__ MbT)
{
  const long i = (long)blockIdx.x * 256 + threadIdx.x;  // 524,288 total
  float s = 0.f;
#pragma unroll
  for (int c = 0; c < 8; c++) s += MTpart[(long)c * 32 * Dh * Dh + i];
  MbT[i] = __float2bfloat16(s * SCALE);
}

// ---- W2[b][o][h*128+e] = sum_d Wout[o][h*128+d] * MbT[b,h][e][d] ----
__global__ __launch_bounds__(256) void k_gemm_w2(
    const bf16* __restrict__ WoutB, const bf16* __restrict__ MbT, bf16* __restrict__ W2)
{
  const int m0 = blockIdx.x * 128;  // o tile
  const int h = blockIdx.y, b = blockIdx.z;
  const int z = b * 8 + h;
  f32x4 acc[4][4];
  gemm_bt_core(WoutB + (long)m0 * Cn + h * Dh, Cn,
               MbT + (long)z * Dh * Dh, Dh, 4, acc);
  store_bf16_tile(acc, W2 + (long)b * Cn * Cn + (long)m0 * Cn + h * Dh, Cn);
}

// ---- out[b][o][s] = sum_c W2[b][o][c] * QT[b][s][c] -> f32 final ----
__global__ __launch_bounds__(256) void k_gemm_out(
    const bf16* __restrict__ W2, const bf16* __restrict__ QT, float* __restrict__ out)
{
  const int m0 = blockIdx.x * 128, n0 = blockIdx.y * 128, b = blockIdx.z;
  f32x4 acc[4][4];
  gemm_bt_core(W2 + (long)b * Cn * Cn + (long)m0 * Cn, Cn,
               QT + (long)b * S * Cn + (long)n0 * Cn, Cn, Cn / 32, acc);
  store_f32_tile(acc, out + (long)b * Cn * S + (long)m0 * S + n0, S);
}

extern "C" void kernel_launch(void* const* d_in, const int* in_sizes, int n_in,
                              void* d_out, int out_size, void* d_ws, size_t ws_size,
                              hipStream_t stream)
{
  const float* x    = (const float*)d_in[0];  // (4,1024,2048) f32
  const float* Wqkv = (const float*)d_in[1];  // (3072,1024)   f32
  const float* Wout = (const float*)d_in[2];  // (1024,1024)   f32
  float* out = (float*)d_out;                 // (4,1024,2048) f32

  char* ws = (char*)d_ws;
  bf16*  KV     = (bf16*)ws;                     // 33,554,432 B
  bf16*  xT     = (bf16*)(ws + 33554432);        // 16,777,216 B
  float* MTpart = (float*)(ws + 33554432);       // aliases xT (dead after kv)
  bf16*  QT     = (bf16*)(ws + 50331648);        // 16,777,216 B
  bf16*  WqkvB  = (bf16*)(ws + 67108864);        //  6,291,456 B
  bf16*  WoutB  = (bf16*)(ws + 73400320);        //  2,097,152 B
  bf16*  MbT    = (bf16*)(ws + 75497472);        //  1,048,576 B
  bf16*  W2     = (bf16*)(ws + 76546048);        //  8,388,608 B (end 84,934,656)

  // weights f32 -> bf16 (one dispatch, float4)
  k_cvt_w<<<dim3(4096), 256, 0, stream>>>(Wqkv, Wout, WqkvB, WoutB);
  // xT[b] = bf16(x[b]^T)
  k_transpose_cvt<<<dim3(64, 32, 4), 256, 0, stream>>>(
      x, xT, (long)1024 * 2048, (long)2048 * 1024);
  // QT directly from the GEMM (A/B swap; no Q transpose kernel)
  k_gemm_qT<<<dim3(16, 8, 4), 256, 0, stream>>>(xT, WqkvB, QT);
  // K,V in (o,s) layout for the MT GEMM
  k_gemm_kv<<<dim3(16, 16, 4), 256, 0, stream>>>(WqkvB, xT, KV);
  // MT partials: K_h . V_h^T over 8 s-chunks (no atomics)
  k_gemm_mt<<<dim3(8, 32), 256, 0, stream>>>(KV, MTpart);
  // MbT = bf16(SCALE * sum of partials)
  k_reduce_mt<<<dim3(2048), 256, 0, stream>>>(MTpart, MbT);
  // W2[b] = Wout . (scale*M): folded per-batch output weights
  k_gemm_w2<<<dim3(8, 8, 4), 256, 0, stream>>>(WoutB, MbT, W2);
  // out[b] = W2[b] . Q[b]  (f32 output)
  k_gemm_out<<<dim3(8, 16, 4), 256, 0, stream>>>(W2, QT, out);
}